// Round 2
// baseline (974.639 us; speedup 1.0000x reference)
//
#include <hip/hip_runtime.h>
#include <stdint.h>

// SimGCL encoder: 3 x { spmm -> +sign(x)*l2norm(threefry_noise)*0.1 -> acc }, out = acc/3
static constexpr int NT    = 100000;   // N_USERS + N_ITEMS
static constexpr int EMB_D = 64;
static constexpr float EPS_F = 0.1f;

// ---------------- threefry-2x32 (matches jax._src.prng) ----------------
__host__ __device__ inline uint32_t rotl32(uint32_t v, int d) {
  return (v << d) | (v >> (32 - d));
}

__host__ __device__ inline void tf2x32(uint32_t k0, uint32_t k1,
                                       uint32_t c0, uint32_t c1,
                                       uint32_t& o0, uint32_t& o1) {
  uint32_t ks0 = k0, ks1 = k1, ks2 = k0 ^ k1 ^ 0x1BD11BDAu;
  uint32_t x0 = c0 + ks0, x1 = c1 + ks1;
  const int ra[4] = {13, 15, 26, 6};
  const int rb[4] = {17, 29, 16, 24};
#pragma unroll
  for (int i = 0; i < 4; i++) { x0 += x1; x1 = rotl32(x1, ra[i]); x1 ^= x0; }
  x0 += ks1; x1 += ks2 + 1u;
#pragma unroll
  for (int i = 0; i < 4; i++) { x0 += x1; x1 = rotl32(x1, rb[i]); x1 ^= x0; }
  x0 += ks2; x1 += ks0 + 2u;
#pragma unroll
  for (int i = 0; i < 4; i++) { x0 += x1; x1 = rotl32(x1, ra[i]); x1 ^= x0; }
  x0 += ks0; x1 += ks1 + 3u;
#pragma unroll
  for (int i = 0; i < 4; i++) { x0 += x1; x1 = rotl32(x1, rb[i]); x1 ^= x0; }
  x0 += ks1; x1 += ks2 + 4u;
#pragma unroll
  for (int i = 0; i < 4; i++) { x0 += x1; x1 = rotl32(x1, ra[i]); x1 ^= x0; }
  x0 += ks2; x1 += ks0 + 5u;
  o0 = x0; o1 = x1;
}

// ---------------- SpMM: y[row[e]][:] += val[e] * x[col[e]][:] ----------------
__global__ __launch_bounds__(256) void spmm_kernel(
    const int* __restrict__ erow, const int* __restrict__ ecol,
    const float* __restrict__ eval_, const float* __restrict__ x,
    float* __restrict__ y, int nE) {
  const int lane  = threadIdx.x & 63;
  const int wave  = (blockIdx.x * blockDim.x + threadIdx.x) >> 6;
  const int nWav  = (gridDim.x * blockDim.x) >> 6;
  for (int e = wave; e < nE; e += nWav) {
    const int r = erow[e];
    const int c = ecol[e];
    const float v = eval_[e];
    const float xv = x[c * EMB_D + lane];
    unsafeAtomicAdd(&y[r * EMB_D + lane], v * xv);
  }
}

// ---------------- noise + accumulate ----------------
// JAX >= 0.4.36 default: jax_threefry_partitionable = True.
// random_bits (32-bit) per element idx: counts = iota(uint64) -> (hi=0, lo=idx);
// (b1, b2) = threefry2x32(key, (0, idx)); bits = b1 ^ b2.
// mode 0: acc  = ego_new
// mode 1: acc += ego_new
// mode 2: acc  = (acc + ego_new) * (1/3)
__global__ __launch_bounds__(256) void noise_acc_kernel(
    float* __restrict__ ego, float* __restrict__ acc,
    uint32_t fk0, uint32_t fk1, int mode) {
  const int row = blockIdx.x * 4 + (threadIdx.x >> 6);
  if (row >= NT) return;
  const int lane = threadIdx.x & 63;
  const int idx  = row * EMB_D + lane;

  uint32_t o0, o1;
  tf2x32(fk0, fk1, 0u, (uint32_t)idx, o0, o1);
  const uint32_t bits = o0 ^ o1;
  const float u = __uint_as_float((bits >> 9) | 0x3F800000u) - 1.0f;

  // row L2 norm across the 64 lanes
  float s = u * u;
#pragma unroll
  for (int m = 1; m < 64; m <<= 1) s += __shfl_xor(s, m, 64);
  const float norm = sqrtf(s);
  const float un = u / fmaxf(norm, 1e-12f);

  const float e  = ego[idx];
  const float sg = (e > 0.0f) ? 1.0f : ((e < 0.0f) ? -1.0f : 0.0f);
  const float en = e + sg * un * EPS_F;
  ego[idx] = en;

  if (mode == 0)      acc[idx] = en;
  else if (mode == 1) acc[idx] = acc[idx] + en;
  else                acc[idx] = (acc[idx] + en) * (1.0f / 3.0f);
}

extern "C" void kernel_launch(void* const* d_in, const int* in_sizes, int n_in,
                              void* d_out, int out_size, void* d_ws, size_t ws_size,
                              hipStream_t stream) {
  const float* ego_in = (const float*)d_in[0];
  const int*   erow   = (const int*)d_in[1];
  const int*   ecol   = (const int*)d_in[2];
  const float* eval_  = (const float*)d_in[3];
  const int nE = in_sizes[1];

  float* out  = (float*)d_out;
  float* bufA = (float*)d_ws;
  float* bufB = bufA + (size_t)NT * EMB_D;
  const size_t bytes = (size_t)NT * EMB_D * sizeof(float);

  // folded keys for layers 0..2: threefry2x32(PRNGKey(42)=(0,42), (0,k))
  // (fold_in is mode-independent)
  uint32_t fk[3][2];
  for (uint32_t k = 0; k < 3; k++) tf2x32(0u, 42u, 0u, k, fk[k][0], fk[k][1]);

  const int spmmBlocks = 2048, spmmThreads = 256;
  const int noiseBlocks = NT / 4, noiseThreads = 256;

  // layer 0
  hipMemsetAsync(bufA, 0, bytes, stream);
  spmm_kernel<<<spmmBlocks, spmmThreads, 0, stream>>>(erow, ecol, eval_, ego_in, bufA, nE);
  noise_acc_kernel<<<noiseBlocks, noiseThreads, 0, stream>>>(bufA, out, fk[0][0], fk[0][1], 0);
  // layer 1
  hipMemsetAsync(bufB, 0, bytes, stream);
  spmm_kernel<<<spmmBlocks, spmmThreads, 0, stream>>>(erow, ecol, eval_, bufA, bufB, nE);
  noise_acc_kernel<<<noiseBlocks, noiseThreads, 0, stream>>>(bufB, out, fk[1][0], fk[1][1], 1);
  // layer 2
  hipMemsetAsync(bufA, 0, bytes, stream);
  spmm_kernel<<<spmmBlocks, spmmThreads, 0, stream>>>(erow, ecol, eval_, bufB, bufA, nE);
  noise_acc_kernel<<<noiseBlocks, noiseThreads, 0, stream>>>(bufA, out, fk[2][0], fk[2][1], 2);
}

// Round 3
// 457.263 us; speedup vs baseline: 2.1315x; 2.1315x over previous
//
#include <hip/hip_runtime.h>
#include <stdint.h>

// SimGCL encoder: 3 x { spmm -> +sign(x)*l2norm(threefry_noise)*0.1 -> acc }, out = acc/3
static constexpr int NT    = 100000;   // N_USERS + N_ITEMS
static constexpr int EMB_D = 64;
static constexpr float EPS_F = 0.1f;

// ---------------- threefry-2x32 (matches jax._src.prng, partitionable mode) ----------------
__host__ __device__ inline uint32_t rotl32(uint32_t v, int d) {
  return (v << d) | (v >> (32 - d));
}

__host__ __device__ inline void tf2x32(uint32_t k0, uint32_t k1,
                                       uint32_t c0, uint32_t c1,
                                       uint32_t& o0, uint32_t& o1) {
  uint32_t ks0 = k0, ks1 = k1, ks2 = k0 ^ k1 ^ 0x1BD11BDAu;
  uint32_t x0 = c0 + ks0, x1 = c1 + ks1;
  const int ra[4] = {13, 15, 26, 6};
  const int rb[4] = {17, 29, 16, 24};
#pragma unroll
  for (int i = 0; i < 4; i++) { x0 += x1; x1 = rotl32(x1, ra[i]); x1 ^= x0; }
  x0 += ks1; x1 += ks2 + 1u;
#pragma unroll
  for (int i = 0; i < 4; i++) { x0 += x1; x1 = rotl32(x1, rb[i]); x1 ^= x0; }
  x0 += ks2; x1 += ks0 + 2u;
#pragma unroll
  for (int i = 0; i < 4; i++) { x0 += x1; x1 = rotl32(x1, ra[i]); x1 ^= x0; }
  x0 += ks0; x1 += ks1 + 3u;
#pragma unroll
  for (int i = 0; i < 4; i++) { x0 += x1; x1 = rotl32(x1, rb[i]); x1 ^= x0; }
  x0 += ks1; x1 += ks2 + 4u;
#pragma unroll
  for (int i = 0; i < 4; i++) { x0 += x1; x1 = rotl32(x1, ra[i]); x1 ^= x0; }
  x0 += ks2; x1 += ks0 + 5u;
  o0 = x0; o1 = x1;
}

// per-element uniform [0,1): bits = b1 ^ b2 of threefry2x32(key, (0, idx))
__device__ inline float tf_uniform(uint32_t fk0, uint32_t fk1, uint32_t idx) {
  uint32_t o0, o1;
  tf2x32(fk0, fk1, 0u, idx, o0, o1);
  uint32_t bits = o0 ^ o1;
  return __uint_as_float((bits >> 9) | 0x3F800000u) - 1.0f;
}

// =====================  CSR build  =====================
__global__ __launch_bounds__(256) void hist_kernel(
    const int* __restrict__ erow, int* __restrict__ cnt, int nE) {
  int e = blockIdx.x * 256 + threadIdx.x;
  if (e < nE) atomicAdd(&cnt[erow[e]], 1);
}

static constexpr int SCAN_CHUNK = 2048;   // elements per block
static constexpr int SCAN_T     = 256;    // threads per block, 8 elems each
static constexpr int SCAN_NB    = (NT + SCAN_CHUNK - 1) / SCAN_CHUNK;  // 49

__global__ __launch_bounds__(SCAN_T) void scan_reduce(
    const int* __restrict__ cnt, int* __restrict__ partial) {
  __shared__ int lds[SCAN_T];
  int base = blockIdx.x * SCAN_CHUNK + threadIdx.x * 8;
  int s = 0;
#pragma unroll
  for (int i = 0; i < 8; i++) { int idx = base + i; if (idx < NT) s += cnt[idx]; }
  lds[threadIdx.x] = s; __syncthreads();
  for (int off = SCAN_T / 2; off > 0; off >>= 1) {
    if (threadIdx.x < off) lds[threadIdx.x] += lds[threadIdx.x + off];
    __syncthreads();
  }
  if (threadIdx.x == 0) partial[blockIdx.x] = lds[0];
}

__global__ __launch_bounds__(64) void scan_offsets(
    const int* __restrict__ partial, int* __restrict__ offsets, int nb) {
  if (threadIdx.x == 0) {
    int run = 0;
    for (int b = 0; b < nb; b++) { offsets[b] = run; run += partial[b]; }
    offsets[nb] = run;
  }
}

__global__ __launch_bounds__(SCAN_T) void scan_write(
    const int* __restrict__ cnt, const int* __restrict__ offsets,
    int* __restrict__ row_ptr, int* __restrict__ cursor) {
  __shared__ int lds[SCAN_T];
  const int tid  = threadIdx.x;
  const int base = blockIdx.x * SCAN_CHUNK + tid * 8;
  int v[8]; int s = 0;
#pragma unroll
  for (int i = 0; i < 8; i++) { int idx = base + i; v[i] = (idx < NT) ? cnt[idx] : 0; s += v[i]; }
  lds[tid] = s; __syncthreads();
  // Hillis-Steele inclusive scan over 256 thread sums
  for (int off = 1; off < SCAN_T; off <<= 1) {
    int t = 0;
    if (tid >= off) t = lds[tid - off];
    __syncthreads();
    if (tid >= off) lds[tid] += t;
    __syncthreads();
  }
  const int excl = lds[tid] - s;
  int run = offsets[blockIdx.x] + excl;
#pragma unroll
  for (int i = 0; i < 8; i++) {
    int idx = base + i;
    if (idx < NT) { row_ptr[idx] = run; cursor[idx] = run; run += v[i]; }
  }
  if (blockIdx.x == gridDim.x - 1 && tid == SCAN_T - 1)
    row_ptr[NT] = offsets[gridDim.x];
}

__global__ __launch_bounds__(256) void scatter_kernel(
    const int* __restrict__ erow, const int* __restrict__ ecol,
    const float* __restrict__ eval_, int* __restrict__ cursor,
    int* __restrict__ scol, float* __restrict__ sval, int nE) {
  int e = blockIdx.x * 256 + threadIdx.x;
  if (e < nE) {
    int r = erow[e];
    int p = atomicAdd(&cursor[r], 1);
    scol[p] = ecol[e];
    sval[p] = eval_[e];
  }
}

// =====================  fused SpMM + noise + accumulate  =====================
// Row-per-wave pull: lane = feature column. Full row is wave-resident ->
// noise + l2norm + sign + acc all in-register.
// mode 0: ego_out = en; acc  = en
// mode 1: ego_out = en; acc += en
// mode 2: (no ego_out)  acc  = (acc + en) * (1/3)
__global__ __launch_bounds__(256) void spmm_noise_kernel(
    const int* __restrict__ row_ptr, const int* __restrict__ scol,
    const float* __restrict__ sval, const float* __restrict__ x,
    float* __restrict__ ego_out, float* __restrict__ acc,
    uint32_t fk0, uint32_t fk1, int mode) {
  const int row = blockIdx.x * 4 + (threadIdx.x >> 6);
  if (row >= NT) return;
  const int lane = threadIdx.x & 63;

  const int beg = row_ptr[row];
  const int end = row_ptr[row + 1];

  float s = 0.0f;
  int j = beg;
  for (; j + 4 <= end; j += 4) {
    const int   c0 = scol[j],   c1 = scol[j+1], c2 = scol[j+2], c3 = scol[j+3];
    const float v0 = sval[j],   v1 = sval[j+1], v2 = sval[j+2], v3 = sval[j+3];
    const float x0 = x[(size_t)c0 * EMB_D + lane];
    const float x1 = x[(size_t)c1 * EMB_D + lane];
    const float x2 = x[(size_t)c2 * EMB_D + lane];
    const float x3 = x[(size_t)c3 * EMB_D + lane];
    s = fmaf(v0, x0, s); s = fmaf(v1, x1, s);
    s = fmaf(v2, x2, s); s = fmaf(v3, x3, s);
  }
  for (; j < end; ++j)
    s = fmaf(sval[j], x[(size_t)scol[j] * EMB_D + lane], s);

  // noise
  const int idx = row * EMB_D + lane;
  const float u = tf_uniform(fk0, fk1, (uint32_t)idx);
  float nsq = u * u;
#pragma unroll
  for (int m = 1; m < 64; m <<= 1) nsq += __shfl_xor(nsq, m, 64);
  const float un = u / fmaxf(sqrtf(nsq), 1e-12f);

  const float sg = (s > 0.0f) ? 1.0f : ((s < 0.0f) ? -1.0f : 0.0f);
  const float en = s + sg * un * EPS_F;

  if (mode == 0)      { ego_out[idx] = en; acc[idx] = en; }
  else if (mode == 1) { ego_out[idx] = en; acc[idx] = acc[idx] + en; }
  else                {                    acc[idx] = (acc[idx] + en) * (1.0f / 3.0f); }
}

// =====================  fallback (R2 atomic path)  =====================
__global__ __launch_bounds__(256) void spmm_kernel(
    const int* __restrict__ erow, const int* __restrict__ ecol,
    const float* __restrict__ eval_, const float* __restrict__ x,
    float* __restrict__ y, int nE) {
  const int lane = threadIdx.x & 63;
  const int wave = (blockIdx.x * blockDim.x + threadIdx.x) >> 6;
  const int nWav = (gridDim.x * blockDim.x) >> 6;
  for (int e = wave; e < nE; e += nWav) {
    const int r = erow[e];
    const int c = ecol[e];
    const float v = eval_[e];
    unsafeAtomicAdd(&y[r * EMB_D + lane], v * x[c * EMB_D + lane]);
  }
}

__global__ __launch_bounds__(256) void noise_acc_kernel(
    float* __restrict__ ego, float* __restrict__ acc,
    uint32_t fk0, uint32_t fk1, int mode) {
  const int row = blockIdx.x * 4 + (threadIdx.x >> 6);
  if (row >= NT) return;
  const int lane = threadIdx.x & 63;
  const int idx  = row * EMB_D + lane;
  const float u = tf_uniform(fk0, fk1, (uint32_t)idx);
  float nsq = u * u;
#pragma unroll
  for (int m = 1; m < 64; m <<= 1) nsq += __shfl_xor(nsq, m, 64);
  const float un = u / fmaxf(sqrtf(nsq), 1e-12f);
  const float e  = ego[idx];
  const float sg = (e > 0.0f) ? 1.0f : ((e < 0.0f) ? -1.0f : 0.0f);
  const float en = e + sg * un * EPS_F;
  ego[idx] = en;
  if (mode == 0)      acc[idx] = en;
  else if (mode == 1) acc[idx] = acc[idx] + en;
  else                acc[idx] = (acc[idx] + en) * (1.0f / 3.0f);
}

extern "C" void kernel_launch(void* const* d_in, const int* in_sizes, int n_in,
                              void* d_out, int out_size, void* d_ws, size_t ws_size,
                              hipStream_t stream) {
  const float* ego_in = (const float*)d_in[0];
  const int*   erow   = (const int*)d_in[1];
  const int*   ecol   = (const int*)d_in[2];
  const float* eval_  = (const float*)d_in[3];
  const int nE = in_sizes[1];

  float* out = (float*)d_out;

  // folded keys for layers 0..2: threefry2x32(PRNGKey(42)=(0,42), (0,k))
  uint32_t fk[3][2];
  for (uint32_t k = 0; k < 3; k++) tf2x32(0u, 42u, 0u, k, fk[k][0], fk[k][1]);

  const size_t egoElems = (size_t)NT * EMB_D;

  // ws layout for CSR path
  float* bufA = (float*)d_ws;                      // NT*64 f32
  float* bufB = bufA + egoElems;                   // NT*64 f32
  int*   scol = (int*)(bufB + egoElems);           // E i32
  float* sval = (float*)(scol + nE);               // E f32
  int*   rptr = (int*)(sval + nE);                 // NT+1
  int*   curs = rptr + (NT + 1);                   // NT (doubles as histogram)
  int*   part = curs + NT;                         // SCAN_NB (pad 64)
  int*   offs = part + 64;                         // SCAN_NB+1 (pad 64)
  const size_t needBytes =
      (char*)(offs + 64) - (char*)d_ws;

  if (ws_size >= needBytes) {
    // ---- CSR build ----
    hipMemsetAsync(curs, 0, (size_t)NT * sizeof(int), stream);
    const int eb = (nE + 255) / 256;
    hist_kernel<<<eb, 256, 0, stream>>>(erow, curs, nE);
    scan_reduce<<<SCAN_NB, SCAN_T, 0, stream>>>(curs, part);
    scan_offsets<<<1, 64, 0, stream>>>(part, offs, SCAN_NB);
    scan_write<<<SCAN_NB, SCAN_T, 0, stream>>>(curs, offs, rptr, curs);
    scatter_kernel<<<eb, 256, 0, stream>>>(erow, ecol, eval_, curs, scol, sval, nE);

    // ---- 3 fused layers ----
    const int nb = (NT + 3) / 4;
    spmm_noise_kernel<<<nb, 256, 0, stream>>>(rptr, scol, sval, ego_in, bufA, out,
                                              fk[0][0], fk[0][1], 0);
    spmm_noise_kernel<<<nb, 256, 0, stream>>>(rptr, scol, sval, bufA, bufB, out,
                                              fk[1][0], fk[1][1], 1);
    spmm_noise_kernel<<<nb, 256, 0, stream>>>(rptr, scol, sval, bufB, nullptr, out,
                                              fk[2][0], fk[2][1], 2);
  } else {
    // ---- fallback: R2 atomic path (needs 2*egoElems floats) ----
    const size_t bytes = egoElems * sizeof(float);
    const int noiseBlocks = (NT + 3) / 4;
    hipMemsetAsync(bufA, 0, bytes, stream);
    spmm_kernel<<<2048, 256, 0, stream>>>(erow, ecol, eval_, ego_in, bufA, nE);
    noise_acc_kernel<<<noiseBlocks, 256, 0, stream>>>(bufA, out, fk[0][0], fk[0][1], 0);
    hipMemsetAsync(bufB, 0, bytes, stream);
    spmm_kernel<<<2048, 256, 0, stream>>>(erow, ecol, eval_, bufA, bufB, nE);
    noise_acc_kernel<<<noiseBlocks, 256, 0, stream>>>(bufB, out, fk[1][0], fk[1][1], 1);
    hipMemsetAsync(bufA, 0, bytes, stream);
    spmm_kernel<<<2048, 256, 0, stream>>>(erow, ecol, eval_, bufB, bufA, nE);
    noise_acc_kernel<<<noiseBlocks, 256, 0, stream>>>(bufA, out, fk[2][0], fk[2][1], 2);
  }
}

// Round 4
// 405.099 us; speedup vs baseline: 2.4059x; 1.1288x over previous
//
#include <hip/hip_runtime.h>
#include <stdint.h>

// SimGCL encoder: 3 x { spmm -> +sign(x)*l2norm(threefry_noise)*0.1 -> acc }, out = acc/3
static constexpr int NT    = 100000;   // N_USERS + N_ITEMS
static constexpr int EMB_D = 64;
static constexpr float EPS_F = 0.1f;

// ---------------- threefry-2x32 (matches jax._src.prng, partitionable mode) ----------------
__host__ __device__ inline uint32_t rotl32(uint32_t v, int d) {
  return (v << d) | (v >> (32 - d));
}

__host__ __device__ inline void tf2x32(uint32_t k0, uint32_t k1,
                                       uint32_t c0, uint32_t c1,
                                       uint32_t& o0, uint32_t& o1) {
  uint32_t ks0 = k0, ks1 = k1, ks2 = k0 ^ k1 ^ 0x1BD11BDAu;
  uint32_t x0 = c0 + ks0, x1 = c1 + ks1;
  const int ra[4] = {13, 15, 26, 6};
  const int rb[4] = {17, 29, 16, 24};
#pragma unroll
  for (int i = 0; i < 4; i++) { x0 += x1; x1 = rotl32(x1, ra[i]); x1 ^= x0; }
  x0 += ks1; x1 += ks2 + 1u;
#pragma unroll
  for (int i = 0; i < 4; i++) { x0 += x1; x1 = rotl32(x1, rb[i]); x1 ^= x0; }
  x0 += ks2; x1 += ks0 + 2u;
#pragma unroll
  for (int i = 0; i < 4; i++) { x0 += x1; x1 = rotl32(x1, ra[i]); x1 ^= x0; }
  x0 += ks0; x1 += ks1 + 3u;
#pragma unroll
  for (int i = 0; i < 4; i++) { x0 += x1; x1 = rotl32(x1, rb[i]); x1 ^= x0; }
  x0 += ks1; x1 += ks2 + 4u;
#pragma unroll
  for (int i = 0; i < 4; i++) { x0 += x1; x1 = rotl32(x1, ra[i]); x1 ^= x0; }
  x0 += ks2; x1 += ks0 + 5u;
  o0 = x0; o1 = x1;
}

// per-element uniform [0,1): bits = b1 ^ b2 of threefry2x32(key, (0, idx))
__device__ inline float tf_uniform(uint32_t fk0, uint32_t fk1, uint32_t idx) {
  uint32_t o0, o1;
  tf2x32(fk0, fk1, 0u, idx, o0, o1);
  uint32_t bits = o0 ^ o1;
  return __uint_as_float((bits >> 9) | 0x3F800000u) - 1.0f;
}

// =====================  CSR build  =====================
__global__ __launch_bounds__(256) void hist_kernel(
    const int* __restrict__ erow, int* __restrict__ cnt, int nE) {
  int e = blockIdx.x * 256 + threadIdx.x;
  if (e < nE) atomicAdd(&cnt[erow[e]], 1);
}

static constexpr int SCAN_CHUNK = 2048;   // elements per block
static constexpr int SCAN_T     = 256;    // threads per block, 8 elems each
static constexpr int SCAN_NB    = (NT + SCAN_CHUNK - 1) / SCAN_CHUNK;  // 49

__global__ __launch_bounds__(SCAN_T) void scan_reduce(
    const int* __restrict__ cnt, int* __restrict__ partial) {
  __shared__ int lds[SCAN_T];
  int base = blockIdx.x * SCAN_CHUNK + threadIdx.x * 8;
  int s = 0;
#pragma unroll
  for (int i = 0; i < 8; i++) { int idx = base + i; if (idx < NT) s += cnt[idx]; }
  lds[threadIdx.x] = s; __syncthreads();
  for (int off = SCAN_T / 2; off > 0; off >>= 1) {
    if (threadIdx.x < off) lds[threadIdx.x] += lds[threadIdx.x + off];
    __syncthreads();
  }
  if (threadIdx.x == 0) partial[blockIdx.x] = lds[0];
}

__global__ __launch_bounds__(64) void scan_offsets(
    const int* __restrict__ partial, int* __restrict__ offsets, int nb) {
  if (threadIdx.x == 0) {
    int run = 0;
    for (int b = 0; b < nb; b++) { offsets[b] = run; run += partial[b]; }
    offsets[nb] = run;
  }
}

__global__ __launch_bounds__(SCAN_T) void scan_write(
    const int* __restrict__ cnt, const int* __restrict__ offsets,
    int* __restrict__ row_ptr, int* __restrict__ cursor) {
  __shared__ int lds[SCAN_T];
  const int tid  = threadIdx.x;
  const int base = blockIdx.x * SCAN_CHUNK + tid * 8;
  int v[8]; int s = 0;
#pragma unroll
  for (int i = 0; i < 8; i++) { int idx = base + i; v[i] = (idx < NT) ? cnt[idx] : 0; s += v[i]; }
  lds[tid] = s; __syncthreads();
  // Hillis-Steele inclusive scan over 256 thread sums
  for (int off = 1; off < SCAN_T; off <<= 1) {
    int t = 0;
    if (tid >= off) t = lds[tid - off];
    __syncthreads();
    if (tid >= off) lds[tid] += t;
    __syncthreads();
  }
  const int excl = lds[tid] - s;
  int run = offsets[blockIdx.x] + excl;
#pragma unroll
  for (int i = 0; i < 8; i++) {
    int idx = base + i;
    if (idx < NT) { row_ptr[idx] = run; cursor[idx] = run; run += v[i]; }
  }
  if (blockIdx.x == gridDim.x - 1 && tid == SCAN_T - 1)
    row_ptr[NT] = offsets[gridDim.x];
}

// packed (col, val-bits) single 8B scattered store per edge
__global__ __launch_bounds__(256) void scatter_kernel(
    const int* __restrict__ erow, const int* __restrict__ ecol,
    const float* __restrict__ eval_, int* __restrict__ cursor,
    int2* __restrict__ pk, int nE) {
  int e = blockIdx.x * 256 + threadIdx.x;
  if (e < nE) {
    int r = erow[e];
    int p = atomicAdd(&cursor[r], 1);
    int2 w; w.x = ecol[e]; w.y = __float_as_int(eval_[e]);
    pk[p] = w;
  }
}

// =====================  fused SpMM + noise + accumulate  =====================
// Row-per-half-wave pull: 32 lanes per row, float2 per lane (features 2l, 2l+1).
// Full row is half-wave-resident -> noise + l2norm + sign + acc in-register.
// mode 0: ego_out = en; acc  = en
// mode 1: ego_out = en; acc += en
// mode 2: (no ego_out)  acc  = (acc + en) * (1/3)
__global__ __launch_bounds__(256) void spmm_noise_kernel(
    const int* __restrict__ row_ptr, const int2* __restrict__ pk,
    const float* __restrict__ x,
    float* __restrict__ ego_out, float* __restrict__ acc,
    uint32_t fk0, uint32_t fk1, int mode) {
  const int row = blockIdx.x * 8 + (threadIdx.x >> 5);
  if (row >= NT) return;
  const int l32 = threadIdx.x & 31;

  const int beg = row_ptr[row];
  const int end = row_ptr[row + 1];

  float s0 = 0.0f, s1 = 0.0f;
  int j = beg;
  for (; j + 4 <= end; j += 4) {
    const int2 p0 = pk[j], p1 = pk[j+1], p2 = pk[j+2], p3 = pk[j+3];
    const float2 x0 = *reinterpret_cast<const float2*>(&x[(size_t)p0.x * EMB_D + 2*l32]);
    const float2 x1 = *reinterpret_cast<const float2*>(&x[(size_t)p1.x * EMB_D + 2*l32]);
    const float2 x2 = *reinterpret_cast<const float2*>(&x[(size_t)p2.x * EMB_D + 2*l32]);
    const float2 x3 = *reinterpret_cast<const float2*>(&x[(size_t)p3.x * EMB_D + 2*l32]);
    const float v0 = __int_as_float(p0.y), v1 = __int_as_float(p1.y);
    const float v2 = __int_as_float(p2.y), v3 = __int_as_float(p3.y);
    s0 = fmaf(v0, x0.x, s0); s1 = fmaf(v0, x0.y, s1);
    s0 = fmaf(v1, x1.x, s0); s1 = fmaf(v1, x1.y, s1);
    s0 = fmaf(v2, x2.x, s0); s1 = fmaf(v2, x2.y, s1);
    s0 = fmaf(v3, x3.x, s0); s1 = fmaf(v3, x3.y, s1);
  }
  for (; j < end; ++j) {
    const int2 p = pk[j];
    const float2 xv = *reinterpret_cast<const float2*>(&x[(size_t)p.x * EMB_D + 2*l32]);
    const float v = __int_as_float(p.y);
    s0 = fmaf(v, xv.x, s0); s1 = fmaf(v, xv.y, s1);
  }

  // noise (features 2*l32 and 2*l32+1 of this row)
  const uint32_t idx = (uint32_t)row * EMB_D + 2 * l32;
  const float u0 = tf_uniform(fk0, fk1, idx);
  const float u1 = tf_uniform(fk0, fk1, idx + 1);
  float nsq = u0 * u0 + u1 * u1;
#pragma unroll
  for (int m = 1; m < 32; m <<= 1) nsq += __shfl_xor(nsq, m);  // stays within 32-group
  const float rinv = 1.0f / fmaxf(sqrtf(nsq), 1e-12f);

  const float sg0 = (s0 > 0.0f) ? 1.0f : ((s0 < 0.0f) ? -1.0f : 0.0f);
  const float sg1 = (s1 > 0.0f) ? 1.0f : ((s1 < 0.0f) ? -1.0f : 0.0f);
  float2 en;
  en.x = s0 + sg0 * (u0 * rinv) * EPS_F;
  en.y = s1 + sg1 * (u1 * rinv) * EPS_F;

  float2* accp = reinterpret_cast<float2*>(&acc[idx]);
  if (mode == 0) {
    *reinterpret_cast<float2*>(&ego_out[idx]) = en;
    *accp = en;
  } else if (mode == 1) {
    *reinterpret_cast<float2*>(&ego_out[idx]) = en;
    float2 a = *accp; a.x += en.x; a.y += en.y; *accp = a;
  } else {
    float2 a = *accp;
    a.x = (a.x + en.x) * (1.0f / 3.0f);
    a.y = (a.y + en.y) * (1.0f / 3.0f);
    *accp = a;
  }
}

// =====================  fallback (R2 atomic path)  =====================
__global__ __launch_bounds__(256) void spmm_kernel(
    const int* __restrict__ erow, const int* __restrict__ ecol,
    const float* __restrict__ eval_, const float* __restrict__ x,
    float* __restrict__ y, int nE) {
  const int lane = threadIdx.x & 63;
  const int wave = (blockIdx.x * blockDim.x + threadIdx.x) >> 6;
  const int nWav = (gridDim.x * blockDim.x) >> 6;
  for (int e = wave; e < nE; e += nWav) {
    const int r = erow[e];
    const int c = ecol[e];
    const float v = eval_[e];
    unsafeAtomicAdd(&y[r * EMB_D + lane], v * x[c * EMB_D + lane]);
  }
}

__global__ __launch_bounds__(256) void noise_acc_kernel(
    float* __restrict__ ego, float* __restrict__ acc,
    uint32_t fk0, uint32_t fk1, int mode) {
  const int row = blockIdx.x * 4 + (threadIdx.x >> 6);
  if (row >= NT) return;
  const int lane = threadIdx.x & 63;
  const int idx  = row * EMB_D + lane;
  const float u = tf_uniform(fk0, fk1, (uint32_t)idx);
  float nsq = u * u;
#pragma unroll
  for (int m = 1; m < 64; m <<= 1) nsq += __shfl_xor(nsq, m, 64);
  const float un = u / fmaxf(sqrtf(nsq), 1e-12f);
  const float e  = ego[idx];
  const float sg = (e > 0.0f) ? 1.0f : ((e < 0.0f) ? -1.0f : 0.0f);
  const float en = e + sg * un * EPS_F;
  ego[idx] = en;
  if (mode == 0)      acc[idx] = en;
  else if (mode == 1) acc[idx] = acc[idx] + en;
  else                acc[idx] = (acc[idx] + en) * (1.0f / 3.0f);
}

extern "C" void kernel_launch(void* const* d_in, const int* in_sizes, int n_in,
                              void* d_out, int out_size, void* d_ws, size_t ws_size,
                              hipStream_t stream) {
  const float* ego_in = (const float*)d_in[0];
  const int*   erow   = (const int*)d_in[1];
  const int*   ecol   = (const int*)d_in[2];
  const float* eval_  = (const float*)d_in[3];
  const int nE = in_sizes[1];

  float* out = (float*)d_out;

  // folded keys for layers 0..2: threefry2x32(PRNGKey(42)=(0,42), (0,k))
  uint32_t fk[3][2];
  for (uint32_t k = 0; k < 3; k++) tf2x32(0u, 42u, 0u, k, fk[k][0], fk[k][1]);

  const size_t egoElems = (size_t)NT * EMB_D;

  // ws layout for CSR path
  float* bufA = (float*)d_ws;                      // NT*64 f32
  float* bufB = bufA + egoElems;                   // NT*64 f32
  int2*  pk   = (int2*)(bufB + egoElems);          // E int2 (8B-aligned: offset 51.2MB)
  int*   rptr = (int*)(pk + nE);                   // NT+1
  int*   curs = rptr + (NT + 1);                   // NT (doubles as histogram)
  int*   part = curs + NT;                         // SCAN_NB (pad 64)
  int*   offs = part + 64;                         // SCAN_NB+1 (pad 64)
  const size_t needBytes = (char*)(offs + 64) - (char*)d_ws;

  if (ws_size >= needBytes) {
    // ---- CSR build ----
    hipMemsetAsync(curs, 0, (size_t)NT * sizeof(int), stream);
    const int eb = (nE + 255) / 256;
    hist_kernel<<<eb, 256, 0, stream>>>(erow, curs, nE);
    scan_reduce<<<SCAN_NB, SCAN_T, 0, stream>>>(curs, part);
    scan_offsets<<<1, 64, 0, stream>>>(part, offs, SCAN_NB);
    scan_write<<<SCAN_NB, SCAN_T, 0, stream>>>(curs, offs, rptr, curs);
    scatter_kernel<<<eb, 256, 0, stream>>>(erow, ecol, eval_, curs, pk, nE);

    // ---- 3 fused layers (8 rows per 256-thread block) ----
    const int nb = (NT + 7) / 8;
    spmm_noise_kernel<<<nb, 256, 0, stream>>>(rptr, pk, ego_in, bufA, out,
                                              fk[0][0], fk[0][1], 0);
    spmm_noise_kernel<<<nb, 256, 0, stream>>>(rptr, pk, bufA, bufB, out,
                                              fk[1][0], fk[1][1], 1);
    spmm_noise_kernel<<<nb, 256, 0, stream>>>(rptr, pk, bufB, nullptr, out,
                                              fk[2][0], fk[2][1], 2);
  } else {
    // ---- fallback: R2 atomic path (needs 2*egoElems floats) ----
    const size_t bytes = egoElems * sizeof(float);
    const int noiseBlocks = (NT + 3) / 4;
    hipMemsetAsync(bufA, 0, bytes, stream);
    spmm_kernel<<<2048, 256, 0, stream>>>(erow, ecol, eval_, ego_in, bufA, nE);
    noise_acc_kernel<<<noiseBlocks, 256, 0, stream>>>(bufA, out, fk[0][0], fk[0][1], 0);
    hipMemsetAsync(bufB, 0, bytes, stream);
    spmm_kernel<<<2048, 256, 0, stream>>>(erow, ecol, eval_, bufA, bufB, nE);
    noise_acc_kernel<<<noiseBlocks, 256, 0, stream>>>(bufB, out, fk[1][0], fk[1][1], 1);
    hipMemsetAsync(bufA, 0, bytes, stream);
    spmm_kernel<<<2048, 256, 0, stream>>>(erow, ecol, eval_, bufB, bufA, nE);
    noise_acc_kernel<<<noiseBlocks, 256, 0, stream>>>(bufA, out, fk[2][0], fk[2][1], 2);
  }
}

// Round 5
// 338.442 us; speedup vs baseline: 2.8798x; 1.1969x over previous
//
#include <hip/hip_runtime.h>
#include <stdint.h>

// SimGCL encoder: 3 x { spmm -> +sign(x)*l2norm(threefry_noise)*0.1 -> acc }, out = acc/3
static constexpr int NT    = 100000;   // N_USERS + N_ITEMS
static constexpr int EMB_D = 64;
static constexpr float EPS_F = 0.1f;

// ---------------- threefry-2x32 (matches jax._src.prng, partitionable mode) ----------------
__host__ __device__ inline uint32_t rotl32(uint32_t v, int d) {
  return (v << d) | (v >> (32 - d));
}

__host__ __device__ inline void tf2x32(uint32_t k0, uint32_t k1,
                                       uint32_t c0, uint32_t c1,
                                       uint32_t& o0, uint32_t& o1) {
  uint32_t ks0 = k0, ks1 = k1, ks2 = k0 ^ k1 ^ 0x1BD11BDAu;
  uint32_t x0 = c0 + ks0, x1 = c1 + ks1;
  const int ra[4] = {13, 15, 26, 6};
  const int rb[4] = {17, 29, 16, 24};
#pragma unroll
  for (int i = 0; i < 4; i++) { x0 += x1; x1 = rotl32(x1, ra[i]); x1 ^= x0; }
  x0 += ks1; x1 += ks2 + 1u;
#pragma unroll
  for (int i = 0; i < 4; i++) { x0 += x1; x1 = rotl32(x1, rb[i]); x1 ^= x0; }
  x0 += ks2; x1 += ks0 + 2u;
#pragma unroll
  for (int i = 0; i < 4; i++) { x0 += x1; x1 = rotl32(x1, ra[i]); x1 ^= x0; }
  x0 += ks0; x1 += ks1 + 3u;
#pragma unroll
  for (int i = 0; i < 4; i++) { x0 += x1; x1 = rotl32(x1, rb[i]); x1 ^= x0; }
  x0 += ks1; x1 += ks2 + 4u;
#pragma unroll
  for (int i = 0; i < 4; i++) { x0 += x1; x1 = rotl32(x1, ra[i]); x1 ^= x0; }
  x0 += ks2; x1 += ks0 + 5u;
  o0 = x0; o1 = x1;
}

// per-element uniform [0,1): bits = b1 ^ b2 of threefry2x32(key, (0, idx))
__device__ inline float tf_uniform(uint32_t fk0, uint32_t fk1, uint32_t idx) {
  uint32_t o0, o1;
  tf2x32(fk0, fk1, 0u, idx, o0, o1);
  uint32_t bits = o0 ^ o1;
  return __uint_as_float((bits >> 9) | 0x3F800000u) - 1.0f;
}

// =====================  CSR build  =====================
// Phase 1: per-edge rank within its row (8 independent atomics in flight per
// thread to hide device-atomic latency); counts fall out in cnt[].
__global__ __launch_bounds__(256) void rank_kernel(
    const int* __restrict__ erow, int* __restrict__ cnt,
    int* __restrict__ rank, int nE) {
  const int base = blockIdx.x * 2048 + threadIdx.x;
  int r[8], rk[8];
#pragma unroll
  for (int i = 0; i < 8; i++) {
    const int e = base + i * 256;
    r[i] = (e < nE) ? erow[e] : -1;
  }
#pragma unroll
  for (int i = 0; i < 8; i++)
    if (r[i] >= 0) rk[i] = atomicAdd(&cnt[r[i]], 1);
#pragma unroll
  for (int i = 0; i < 8; i++) {
    const int e = base + i * 256;
    if (e < nE) rank[e] = rk[i];
  }
}

static constexpr int SCAN_CHUNK = 2048;   // elements per block
static constexpr int SCAN_T     = 256;    // threads per block, 8 elems each
static constexpr int SCAN_NB    = (NT + SCAN_CHUNK - 1) / SCAN_CHUNK;  // 49

__global__ __launch_bounds__(SCAN_T) void scan_reduce(
    const int* __restrict__ cnt, int* __restrict__ partial) {
  __shared__ int lds[SCAN_T];
  int base = blockIdx.x * SCAN_CHUNK + threadIdx.x * 8;
  int s = 0;
#pragma unroll
  for (int i = 0; i < 8; i++) { int idx = base + i; if (idx < NT) s += cnt[idx]; }
  lds[threadIdx.x] = s; __syncthreads();
  for (int off = SCAN_T / 2; off > 0; off >>= 1) {
    if (threadIdx.x < off) lds[threadIdx.x] += lds[threadIdx.x + off];
    __syncthreads();
  }
  if (threadIdx.x == 0) partial[blockIdx.x] = lds[0];
}

__global__ __launch_bounds__(64) void scan_offsets(
    const int* __restrict__ partial, int* __restrict__ offsets, int nb) {
  if (threadIdx.x == 0) {
    int run = 0;
    for (int b = 0; b < nb; b++) { offsets[b] = run; run += partial[b]; }
    offsets[nb] = run;
  }
}

__global__ __launch_bounds__(SCAN_T) void scan_write(
    const int* __restrict__ cnt, const int* __restrict__ offsets,
    int* __restrict__ row_ptr) {
  __shared__ int lds[SCAN_T];
  const int tid  = threadIdx.x;
  const int base = blockIdx.x * SCAN_CHUNK + tid * 8;
  int v[8]; int s = 0;
#pragma unroll
  for (int i = 0; i < 8; i++) { int idx = base + i; v[i] = (idx < NT) ? cnt[idx] : 0; s += v[i]; }
  lds[tid] = s; __syncthreads();
  // Hillis-Steele inclusive scan over 256 thread sums
  for (int off = 1; off < SCAN_T; off <<= 1) {
    int t = 0;
    if (tid >= off) t = lds[tid - off];
    __syncthreads();
    if (tid >= off) lds[tid] += t;
    __syncthreads();
  }
  const int excl = lds[tid] - s;
  int run = offsets[blockIdx.x] + excl;
#pragma unroll
  for (int i = 0; i < 8; i++) {
    int idx = base + i;
    if (idx < NT) { row_ptr[idx] = run; run += v[i]; }
  }
  if (blockIdx.x == gridDim.x - 1 && tid == SCAN_T - 1)
    row_ptr[NT] = offsets[gridDim.x];
}

// Phase 2: atomic-free scatter — position is row_ptr[r] + rank[e].
// All reads coalesced; one 8B scattered store per edge, 8-way unrolled.
__global__ __launch_bounds__(256) void scatter2_kernel(
    const int* __restrict__ erow, const int* __restrict__ ecol,
    const float* __restrict__ eval_, const int* __restrict__ rank,
    const int* __restrict__ rptr, int2* __restrict__ pk, int nE) {
  const int base = blockIdx.x * 2048 + threadIdx.x;
#pragma unroll
  for (int i = 0; i < 8; i++) {
    const int e = base + i * 256;
    if (e < nE) {
      const int r = erow[e];
      const int p = rptr[r] + rank[e];
      int2 w; w.x = ecol[e]; w.y = __float_as_int(eval_[e]);
      pk[p] = w;
    }
  }
}

// =====================  fused SpMM + noise + accumulate  =====================
// Row-per-half-wave pull: 32 lanes per row, float2 per lane (features 2l, 2l+1).
// mode 0: ego_out = en; acc  = en
// mode 1: ego_out = en; acc += en
// mode 2: (no ego_out)  acc  = (acc + en) * (1/3)
__global__ __launch_bounds__(256) void spmm_noise_kernel(
    const int* __restrict__ row_ptr, const int2* __restrict__ pk,
    const float* __restrict__ x,
    float* __restrict__ ego_out, float* __restrict__ acc,
    uint32_t fk0, uint32_t fk1, int mode) {
  const int row = blockIdx.x * 8 + (threadIdx.x >> 5);
  if (row >= NT) return;
  const int l32 = threadIdx.x & 31;

  const int beg = row_ptr[row];
  const int end = row_ptr[row + 1];

  float s0 = 0.0f, s1 = 0.0f;
  int j = beg;
  for (; j + 8 <= end; j += 8) {
    int2 p[8]; float2 xv[8];
#pragma unroll
    for (int i = 0; i < 8; i++) p[i] = pk[j + i];
#pragma unroll
    for (int i = 0; i < 8; i++)
      xv[i] = *reinterpret_cast<const float2*>(&x[(size_t)p[i].x * EMB_D + 2 * l32]);
#pragma unroll
    for (int i = 0; i < 8; i++) {
      const float v = __int_as_float(p[i].y);
      s0 = fmaf(v, xv[i].x, s0); s1 = fmaf(v, xv[i].y, s1);
    }
  }
  for (; j + 2 <= end; j += 2) {
    const int2 p0 = pk[j], p1 = pk[j + 1];
    const float2 x0 = *reinterpret_cast<const float2*>(&x[(size_t)p0.x * EMB_D + 2 * l32]);
    const float2 x1 = *reinterpret_cast<const float2*>(&x[(size_t)p1.x * EMB_D + 2 * l32]);
    const float v0 = __int_as_float(p0.y), v1 = __int_as_float(p1.y);
    s0 = fmaf(v0, x0.x, s0); s1 = fmaf(v0, x0.y, s1);
    s0 = fmaf(v1, x1.x, s0); s1 = fmaf(v1, x1.y, s1);
  }
  if (j < end) {
    const int2 p = pk[j];
    const float2 xv = *reinterpret_cast<const float2*>(&x[(size_t)p.x * EMB_D + 2 * l32]);
    const float v = __int_as_float(p.y);
    s0 = fmaf(v, xv.x, s0); s1 = fmaf(v, xv.y, s1);
  }

  // noise (features 2*l32 and 2*l32+1 of this row)
  const uint32_t idx = (uint32_t)row * EMB_D + 2 * l32;
  const float u0 = tf_uniform(fk0, fk1, idx);
  const float u1 = tf_uniform(fk0, fk1, idx + 1);
  float nsq = u0 * u0 + u1 * u1;
#pragma unroll
  for (int m = 1; m < 32; m <<= 1) nsq += __shfl_xor(nsq, m);  // stays within 32-group
  const float rinv = 1.0f / fmaxf(sqrtf(nsq), 1e-12f);

  const float sg0 = (s0 > 0.0f) ? 1.0f : ((s0 < 0.0f) ? -1.0f : 0.0f);
  const float sg1 = (s1 > 0.0f) ? 1.0f : ((s1 < 0.0f) ? -1.0f : 0.0f);
  float2 en;
  en.x = s0 + sg0 * (u0 * rinv) * EPS_F;
  en.y = s1 + sg1 * (u1 * rinv) * EPS_F;

  float2* accp = reinterpret_cast<float2*>(&acc[idx]);
  if (mode == 0) {
    *reinterpret_cast<float2*>(&ego_out[idx]) = en;
    *accp = en;
  } else if (mode == 1) {
    *reinterpret_cast<float2*>(&ego_out[idx]) = en;
    float2 a = *accp; a.x += en.x; a.y += en.y; *accp = a;
  } else {
    float2 a = *accp;
    a.x = (a.x + en.x) * (1.0f / 3.0f);
    a.y = (a.y + en.y) * (1.0f / 3.0f);
    *accp = a;
  }
}

// =====================  fallback (R2 atomic path)  =====================
__global__ __launch_bounds__(256) void spmm_kernel(
    const int* __restrict__ erow, const int* __restrict__ ecol,
    const float* __restrict__ eval_, const float* __restrict__ x,
    float* __restrict__ y, int nE) {
  const int lane = threadIdx.x & 63;
  const int wave = (blockIdx.x * blockDim.x + threadIdx.x) >> 6;
  const int nWav = (gridDim.x * blockDim.x) >> 6;
  for (int e = wave; e < nE; e += nWav) {
    const int r = erow[e];
    const int c = ecol[e];
    const float v = eval_[e];
    unsafeAtomicAdd(&y[r * EMB_D + lane], v * x[c * EMB_D + lane]);
  }
}

__global__ __launch_bounds__(256) void noise_acc_kernel(
    float* __restrict__ ego, float* __restrict__ acc,
    uint32_t fk0, uint32_t fk1, int mode) {
  const int row = blockIdx.x * 4 + (threadIdx.x >> 6);
  if (row >= NT) return;
  const int lane = threadIdx.x & 63;
  const int idx  = row * EMB_D + lane;
  const float u = tf_uniform(fk0, fk1, (uint32_t)idx);
  float nsq = u * u;
#pragma unroll
  for (int m = 1; m < 64; m <<= 1) nsq += __shfl_xor(nsq, m, 64);
  const float un = u / fmaxf(sqrtf(nsq), 1e-12f);
  const float e  = ego[idx];
  const float sg = (e > 0.0f) ? 1.0f : ((e < 0.0f) ? -1.0f : 0.0f);
  const float en = e + sg * un * EPS_F;
  ego[idx] = en;
  if (mode == 0)      acc[idx] = en;
  else if (mode == 1) acc[idx] = acc[idx] + en;
  else                acc[idx] = (acc[idx] + en) * (1.0f / 3.0f);
}

extern "C" void kernel_launch(void* const* d_in, const int* in_sizes, int n_in,
                              void* d_out, int out_size, void* d_ws, size_t ws_size,
                              hipStream_t stream) {
  const float* ego_in = (const float*)d_in[0];
  const int*   erow   = (const int*)d_in[1];
  const int*   ecol   = (const int*)d_in[2];
  const float* eval_  = (const float*)d_in[3];
  const int nE = in_sizes[1];

  float* out = (float*)d_out;

  // folded keys for layers 0..2: threefry2x32(PRNGKey(42)=(0,42), (0,k))
  uint32_t fk[3][2];
  for (uint32_t k = 0; k < 3; k++) tf2x32(0u, 42u, 0u, k, fk[k][0], fk[k][1]);

  const size_t egoElems = (size_t)NT * EMB_D;

  // ws layout for CSR path
  float* bufA = (float*)d_ws;                      // NT*64 f32   (layer0/2 ego)
  float* bufB = bufA + egoElems;                   // NT*64 f32   (layer1 ego)
  int2*  pk   = (int2*)(bufB + egoElems);          // E int2
  int*   rptr = (int*)(pk + nE);                   // NT+1
  int*   cnt  = rptr + (NT + 1);                   // NT
  int*   part = cnt + NT;                          // SCAN_NB (pad 64)
  int*   offs = part + 64;                         // SCAN_NB+1 (pad 64)
  const size_t needBytes = (char*)(offs + 64) - (char*)d_ws;

  // rank[] is only live during the build (before layer-0 writes bufA) -> alias
  int* rank = (int*)bufA;

  if (ws_size >= needBytes) {
    // ---- CSR build ----
    hipMemsetAsync(cnt, 0, (size_t)NT * sizeof(int), stream);
    const int eb8 = (nE + 2047) / 2048;
    rank_kernel<<<eb8, 256, 0, stream>>>(erow, cnt, rank, nE);
    scan_reduce<<<SCAN_NB, SCAN_T, 0, stream>>>(cnt, part);
    scan_offsets<<<1, 64, 0, stream>>>(part, offs, SCAN_NB);
    scan_write<<<SCAN_NB, SCAN_T, 0, stream>>>(cnt, offs, rptr);
    scatter2_kernel<<<eb8, 256, 0, stream>>>(erow, ecol, eval_, rank, rptr, pk, nE);

    // ---- 3 fused layers (8 rows per 256-thread block) ----
    const int nb = (NT + 7) / 8;
    spmm_noise_kernel<<<nb, 256, 0, stream>>>(rptr, pk, ego_in, bufA, out,
                                              fk[0][0], fk[0][1], 0);
    spmm_noise_kernel<<<nb, 256, 0, stream>>>(rptr, pk, bufA, bufB, out,
                                              fk[1][0], fk[1][1], 1);
    spmm_noise_kernel<<<nb, 256, 0, stream>>>(rptr, pk, bufB, nullptr, out,
                                              fk[2][0], fk[2][1], 2);
  } else {
    // ---- fallback: R2 atomic path (needs 2*egoElems floats) ----
    const size_t bytes = egoElems * sizeof(float);
    const int noiseBlocks = (NT + 3) / 4;
    hipMemsetAsync(bufA, 0, bytes, stream);
    spmm_kernel<<<2048, 256, 0, stream>>>(erow, ecol, eval_, ego_in, bufA, nE);
    noise_acc_kernel<<<noiseBlocks, 256, 0, stream>>>(bufA, out, fk[0][0], fk[0][1], 0);
    hipMemsetAsync(bufB, 0, bytes, stream);
    spmm_kernel<<<2048, 256, 0, stream>>>(erow, ecol, eval_, bufA, bufB, nE);
    noise_acc_kernel<<<noiseBlocks, 256, 0, stream>>>(bufB, out, fk[1][0], fk[1][1], 1);
    hipMemsetAsync(bufA, 0, bytes, stream);
    spmm_kernel<<<2048, 256, 0, stream>>>(erow, ecol, eval_, bufB, bufA, nE);
    noise_acc_kernel<<<noiseBlocks, 256, 0, stream>>>(bufA, out, fk[2][0], fk[2][1], 2);
  }
}